// Round 2
// baseline (461.086 us; speedup 1.0000x reference)
//
#include <hip/hip_runtime.h>

#define BATCH 8
#define NPTS 4096
#define NROWS (BATCH*NPTS)   // 32768
#define KNB 16
#define NC 128

typedef __attribute__((ext_vector_type(8))) short bf16x8;
typedef __attribute__((ext_vector_type(4))) float f32x4;

static __device__ __forceinline__ unsigned short f2bf(float f) {
  unsigned u = __float_as_uint(f);
  u = u + 0x7fffu + ((u >> 16) & 1u);   // round-to-nearest-even
  return (unsigned short)(u >> 16);
}

// Distance formula — MUST remain bit-identical everywhere it is evaluated
// (matches XLA's (sq_m + sq_n) - 2*dot with no contraction).
static __device__ __forceinline__ float dist_f(const float4 pm, const float4 p) {
  #pragma clang fp contract(off)
  float dot = pm.x*p.x + pm.y*p.y + pm.z*p.z;
  return (pm.w + p.w) - 2.0f*dot;
}

static __device__ __forceinline__ unsigned int f2ord(float f) {
  int t = __float_as_int(f);
  return (unsigned int)(t ^ ((t >> 31) | 0x80000000));
}

// ---------------------------------------------------------------- prep
__global__ __launch_bounds__(256) void prep_kernel(
    const float* __restrict__ xyz, const float* __restrict__ W1,
    const float* __restrict__ W2, float4* __restrict__ xyzw,
    unsigned short* __restrict__ W1bf, unsigned short* __restrict__ W2bf)
{
  int i = blockIdx.x * 256 + threadIdx.x;
  if (i < NROWS) {
    #pragma clang fp contract(off)
    float x = xyz[3*i], y = xyz[3*i+1], z = xyz[3*i+2];
    float sq = x*x + y*y + z*z;
    xyzw[i] = make_float4(x, y, z, sq);
  }
  if (i < NC*NC) {
    W1bf[i] = f2bf(W1[i]);
    W2bf[i] = f2bf(W2[i]);
  }
}

// ---------------------------------------------------------------- topk
// One wave per (b,m). Streaming two-pass threshold select + one bitonic sort.
// Pass1: per-lane max (no d[] storage -> low VGPR, 8 waves/SIMD).
// Tm = exact 17th largest of the 64 lane maxima (radix binary search).
//      Tm <= true 17th largest of all 4096, and count(>=Tm) >= 17.
// Pass2: mask of d >= Tm, compact (value,index) into LDS (<=64 for this data,
//        clamped for memory safety).
// Bitonic sort 64 lanes desc by (value, then smaller index) == top_k order.
// Lane 0 = rank 0 (the dropped farthest); lanes 1..16 emit coords.
__global__ __launch_bounds__(256, 8) void topk_kernel(
    const float4* __restrict__ xyzw, float4* __restrict__ grouped4)
{
  __shared__ unsigned int cu_s[4][64];
  __shared__ int          cn_s[4][64];

  const int lane = threadIdx.x & 63;
  const int w    = threadIdx.x >> 6;
  const int wid  = blockIdx.x * 4 + w;
  const int b    = wid >> 12;          // /4096
  const int m    = wid & (NPTS - 1);
  const float4* base = xyzw + (size_t)b * NPTS;

  const float4 pm = base[m];

  // ---- pass 1: per-lane max over 64 candidates
  float v1 = -3.0e38f;
  #pragma unroll
  for (int j = 0; j < 64; ++j) {
    float dj = dist_f(pm, base[j*64 + lane]);
    v1 = fmaxf(v1, dj);
  }

  // ---- exact 17th largest of the 64 lane maxima (order-preserving uint)
  unsigned int u1 = f2ord(v1);
  unsigned int cur = 0u;
  #pragma unroll 1
  for (int bit = 31; bit >= 0; --bit) {
    unsigned int cand = cur | (1u << bit);
    if (__popcll(__ballot(u1 >= cand)) >= 17) cur = cand;
  }
  // back to float threshold (inverse of f2ord)
  unsigned int ob = (cur & 0x80000000u) ? (cur ^ 0x80000000u) : ~cur;
  const float tmf = __uint_as_float(ob);

  // ---- pass 2: candidate mask (d >= Tm)
  unsigned long long mm = 0ull;
  #pragma unroll
  for (int j = 0; j < 64; ++j) {
    float dj = dist_f(pm, base[j*64 + lane]);
    if (dj >= tmf) mm |= (1ull << j);
  }
  int c = __popcll(mm);

  // exclusive prefix over lanes -> write base; ctot = total candidates
  int pos = c;
  #pragma unroll
  for (int d = 1; d < 64; d <<= 1) {
    int t = __shfl_up(pos, d);
    if (lane >= d) pos += t;
  }
  int ctot = __shfl(pos, 63);
  pos -= c;

  // compact candidates to LDS (recompute value bit-exactly)
  while (__ballot(mm != 0ull)) {
    if (mm) {
      int j = __ffsll(mm) - 1;
      mm &= (mm - 1ull);
      int n = (j << 6) | lane;
      float dj = dist_f(pm, base[n]);
      if (pos < 64) { cu_s[w][pos] = f2ord(dj); cn_s[w][pos] = n; }
      ++pos;
    }
  }

  // load one candidate per lane (pad lanes sort last)
  unsigned int su = 0u;
  int sn = 0x7FFFFFFF;
  if (lane < ctot) { su = cu_s[w][lane]; sn = cn_s[w][lane]; }

  // ---- bitonic sort, descending by (su, then smaller sn)
  #pragma unroll
  for (int k = 2; k <= 64; k <<= 1) {
    #pragma unroll
    for (int s = k >> 1; s >= 1; s >>= 1) {
      unsigned int ou = __shfl_xor(su, s);
      int          on = __shfl_xor(sn, s);
      bool myMax = ((lane & k) == 0) == ((lane & s) == 0);
      bool beats = (ou > su) || (ou == su && on < sn);
      bool take  = myMax ? beats : !beats;
      su = take ? ou : su;
      sn = take ? on : sn;
    }
  }

  // lanes 1..16 hold ranks 1..16
  if (lane >= 1 && lane <= KNB) {
    grouped4[(size_t)wid * KNB + (lane - 1)] = base[sn];
  }
}

// ---------------------------------------------------------------- mlp
// (unchanged from previous round)
__global__ __launch_bounds__(256) void mlp_kernel(
    const float4* __restrict__ grouped4,
    const float*  __restrict__ W0, const float* __restrict__ b0,
    const unsigned short* __restrict__ W1bf, const float* __restrict__ b1,
    const unsigned short* __restrict__ W2bf, const float* __restrict__ b2,
    float* __restrict__ out)
{
  __shared__ float4 g4s[128];
  __shared__ float  W0s[128*4];
  __shared__ float  b0s[128], b1s[128], b2s[128];
  __shared__ unsigned short act[128*128];   // 32 KB

  const int t    = threadIdx.x;
  const int lane = t & 63;
  const int w    = t >> 6;
  const int lr   = lane & 15;
  const int lg   = lane >> 4;
  const int row_base = blockIdx.x * 8;

  if (t < 128) {
    g4s[t] = grouped4[(size_t)row_base * KNB + t];
    float4 w0r;
    w0r.x = W0[t*3+0]; w0r.y = W0[t*3+1]; w0r.z = W0[t*3+2]; w0r.w = 0.0f;
    *(float4*)&W0s[t*4] = w0r;
    b0s[t] = b0[t];
    b1s[t] = b1[t];
    b2s[t] = b2[t];
  }
  __syncthreads();

  // ---- layer 0 (fp32 vector, C=3), write act as bf16
  {
    int r  = t >> 1;
    int cb = (t & 1) * 64;
    float4 g = g4s[r];
    int swz = (r & 7) << 3;
    #pragma unroll
    for (int cc = 0; cc < 8; ++cc) {
      int c0 = cb + cc*8;
      unsigned int pk[4];
      #pragma unroll
      for (int pair = 0; pair < 4; ++pair) {
        unsigned int lo, hi;
        {
          int o = c0 + pair*2;
          float v = b0s[o] + g.x*W0s[o*4] + g.y*W0s[o*4+1] + g.z*W0s[o*4+2];
          lo = f2bf(fmaxf(v, 0.0f));
          o++;
          float v2 = b0s[o] + g.x*W0s[o*4] + g.y*W0s[o*4+1] + g.z*W0s[o*4+2];
          hi = f2bf(fmaxf(v2, 0.0f));
        }
        pk[pair] = lo | (hi << 16);
      }
      uint4 q = make_uint4(pk[0], pk[1], pk[2], pk[3]);
      *(uint4*)&act[r*128 + (c0 ^ swz)] = q;
    }
  }

  const int rt0 = w*2, rt1 = w*2 + 1;
  const int aswz = (lr & 7) << 3;

  // ---- layer 1 (bf16 MFMA), relu, in-place act update
  {
    f32x4 acc[2][8];
    #pragma unroll
    for (int rr = 0; rr < 2; ++rr)
      #pragma unroll
      for (int ct = 0; ct < 8; ++ct)
        acc[rr][ct] = (f32x4){0.f, 0.f, 0.f, 0.f};

    #pragma unroll
    for (int ks = 0; ks < 4; ++ks) {
      int c0 = ks*32 + lg*8;
      bf16x8 a0 = *(const bf16x8*)&act[(rt0*16 + lr)*128 + (c0 ^ aswz)];
      bf16x8 a1 = *(const bf16x8*)&act[(rt1*16 + lr)*128 + (c0 ^ aswz)];
      #pragma unroll
      for (int ct = 0; ct < 8; ++ct) {
        int o = ct*16 + lr;
        bf16x8 bb = *(const bf16x8*)&W1bf[o*128 + c0];
        acc[0][ct] = __builtin_amdgcn_mfma_f32_16x16x32_bf16(a0, bb, acc[0][ct], 0, 0, 0);
        acc[1][ct] = __builtin_amdgcn_mfma_f32_16x16x32_bf16(a1, bb, acc[1][ct], 0, 0, 0);
      }
    }
    #pragma unroll
    for (int rr = 0; rr < 2; ++rr) {
      int rt = rt0 + rr;
      #pragma unroll
      for (int ct = 0; ct < 8; ++ct) {
        int col  = ct*16 + lr;
        float bias = b1s[col];
        #pragma unroll
        for (int i = 0; i < 4; ++i) {
          int row = rt*16 + lg*4 + i;
          float v = acc[rr][ct][i] + bias;
          v = fmaxf(v, 0.0f);
          act[row*128 + (col ^ ((row & 7) << 3))] = f2bf(v);
        }
      }
    }
  }

  // ---- layer 2 (bf16 MFMA), bias, max over k, store
  {
    f32x4 acc[2][8];
    #pragma unroll
    for (int rr = 0; rr < 2; ++rr)
      #pragma unroll
      for (int ct = 0; ct < 8; ++ct)
        acc[rr][ct] = (f32x4){0.f, 0.f, 0.f, 0.f};

    #pragma unroll
    for (int ks = 0; ks < 4; ++ks) {
      int c0 = ks*32 + lg*8;
      bf16x8 a0 = *(const bf16x8*)&act[(rt0*16 + lr)*128 + (c0 ^ aswz)];
      bf16x8 a1 = *(const bf16x8*)&act[(rt1*16 + lr)*128 + (c0 ^ aswz)];
      #pragma unroll
      for (int ct = 0; ct < 8; ++ct) {
        int o = ct*16 + lr;
        bf16x8 bb = *(const bf16x8*)&W2bf[o*128 + c0];
        acc[0][ct] = __builtin_amdgcn_mfma_f32_16x16x32_bf16(a0, bb, acc[0][ct], 0, 0, 0);
        acc[1][ct] = __builtin_amdgcn_mfma_f32_16x16x32_bf16(a1, bb, acc[1][ct], 0, 0, 0);
      }
    }
    #pragma unroll
    for (int rr = 0; rr < 2; ++rr) {
      int p = rt0 + rr;
      #pragma unroll
      for (int ct = 0; ct < 8; ++ct) {
        int col = ct*16 + lr;
        float bias = b2s[col];
        float v0 = acc[rr][ct][0] + bias;
        float va = acc[rr][ct][1] + bias;
        float vb = acc[rr][ct][2] + bias;
        float vc = acc[rr][ct][3] + bias;
        float mx = fmaxf(fmaxf(v0, va), fmaxf(vb, vc));
        mx = fmaxf(mx, __shfl_xor(mx, 16));
        mx = fmaxf(mx, __shfl_xor(mx, 32));
        if (lg == 0) out[(size_t)(row_base + p)*128 + col] = mx;
      }
    }
  }
}

// ---------------------------------------------------------------- launch
extern "C" void kernel_launch(void* const* d_in, const int* in_sizes, int n_in,
                              void* d_out, int out_size, void* d_ws, size_t ws_size,
                              hipStream_t stream) {
  const float* xyz = (const float*)d_in[0];
  const float* W0  = (const float*)d_in[1];
  const float* b0  = (const float*)d_in[2];
  const float* W1  = (const float*)d_in[3];
  const float* b1  = (const float*)d_in[4];
  const float* W2  = (const float*)d_in[5];
  const float* b2  = (const float*)d_in[6];
  float* out = (float*)d_out;

  char* ws = (char*)d_ws;
  float4* xyzw     = (float4*)ws;                              // 512 KB
  float4* grouped4 = (float4*)(ws + (size_t)NROWS*16);         // 8 MB
  unsigned short* W1bf = (unsigned short*)(ws + (size_t)NROWS*16 + (size_t)NROWS*KNB*16);
  unsigned short* W2bf = W1bf + NC*NC;                         // 32 KB each

  prep_kernel<<<NROWS/256, 256, 0, stream>>>(xyz, W1, W2, xyzw, W1bf, W2bf);
  topk_kernel<<<NROWS/4, 256, 0, stream>>>(xyzw, grouped4);
  mlp_kernel<<<NROWS/8, 256, 0, stream>>>(grouped4, W0, b0, W1bf, b1, W2bf, b2, out);
}

// Round 3
// 261.353 us; speedup vs baseline: 1.7642x; 1.7642x over previous
//
#include <hip/hip_runtime.h>

#define BATCH 8
#define NPTS 4096
#define NROWS (BATCH*NPTS)   // 32768
#define KNB 16
#define NC 128

typedef __attribute__((ext_vector_type(8))) short bf16x8;
typedef __attribute__((ext_vector_type(4))) float f32x4;

static __device__ __forceinline__ unsigned short f2bf(float f) {
  unsigned u = __float_as_uint(f);
  u = u + 0x7fffu + ((u >> 16) & 1u);   // round-to-nearest-even
  return (unsigned short)(u >> 16);
}

// Distance formula — MUST remain bit-identical everywhere it is evaluated
// (matches XLA's (sq_m + sq_n) - 2*dot with no contraction).
static __device__ __forceinline__ float dist_f(const float4 pm, const float4 p) {
  #pragma clang fp contract(off)
  float dot = pm.x*p.x + pm.y*p.y + pm.z*p.z;
  return (pm.w + p.w) - 2.0f*dot;
}

static __device__ __forceinline__ unsigned int f2ord(float f) {
  int t = __float_as_int(f);
  return (unsigned int)(t ^ ((t >> 31) | 0x80000000));
}

// ---------------------------------------------------------------- prep
__global__ __launch_bounds__(256) void prep_kernel(
    const float* __restrict__ xyz, const float* __restrict__ W1,
    const float* __restrict__ W2, float4* __restrict__ xyzw,
    unsigned short* __restrict__ W1bf, unsigned short* __restrict__ W2bf)
{
  int i = blockIdx.x * 256 + threadIdx.x;
  if (i < NROWS) {
    #pragma clang fp contract(off)
    float x = xyz[3*i], y = xyz[3*i+1], z = xyz[3*i+2];
    float sq = x*x + y*y + z*z;
    xyzw[i] = make_float4(x, y, z, sq);
  }
  if (i < NC*NC) {
    W1bf[i] = f2bf(W1[i]);
    W2bf[i] = f2bf(W2[i]);
  }
}

// ---------------------------------------------------------------- topk
// One wave per (b,m). R1's register-resident distance pass (known-good:
// VGPR~80, no scratch, FETCH~2MB) + R2's parallel selection machinery
// (known-correct), applied to registers:
//   d[64] in regs -> lane max -> exact 17th-largest of lane maxima via
//   radix ballot (Tm <= true 17th of all 4096; count(>=Tm) >= 17) ->
//   static-indexed compaction of d[j] >= Tm into LDS -> 64-lane bitonic
//   sort desc by (value, smaller index) == jax top_k order.
// Lane 0 = rank 0 (dropped); lanes 1..16 emit coords.
__global__ __launch_bounds__(256) void topk_kernel(
    const float4* __restrict__ xyzw, float4* __restrict__ grouped4)
{
  __shared__ unsigned int cu_s[4][64];
  __shared__ int          cn_s[4][64];

  const int lane = threadIdx.x & 63;
  const int w    = threadIdx.x >> 6;
  const int wid  = blockIdx.x * 4 + w;
  const int b    = wid >> 12;          // /4096
  const int m    = wid & (NPTS - 1);
  const float4* base = xyzw + (size_t)b * NPTS;

  const float4 pm = base[m];

  // ---- single streaming pass, distances kept in registers (as R1)
  float d[64];
  #pragma unroll
  for (int j = 0; j < 64; ++j) {
    d[j] = dist_f(pm, base[j*64 + lane]);
  }

  // ---- per-lane max (registers, cheap)
  float v1 = d[0];
  #pragma unroll
  for (int j = 1; j < 64; ++j) v1 = fmaxf(v1, d[j]);

  // ---- exact 17th largest of the 64 lane maxima (order-preserving uint)
  unsigned int u1 = f2ord(v1);
  unsigned int cur = 0u;
  #pragma unroll 1
  for (int bit = 31; bit >= 0; --bit) {
    unsigned int cand = cur | (1u << bit);
    if (__popcll(__ballot(u1 >= cand)) >= 17) cur = cand;
  }
  unsigned int ob = (cur & 0x80000000u) ? (cur ^ 0x80000000u) : ~cur;
  const float tmf = __uint_as_float(ob);

  // ---- per-lane candidate count (d[j] >= Tm)
  int c = 0;
  #pragma unroll
  for (int j = 0; j < 64; ++j) c += (d[j] >= tmf) ? 1 : 0;

  // exclusive prefix over lanes; ctot = total candidates
  int pos = c;
  #pragma unroll
  for (int dd = 1; dd < 64; dd <<= 1) {
    int t = __shfl_up(pos, dd);
    if (lane >= dd) pos += t;
  }
  int ctot = __shfl(pos, 63);
  pos -= c;

  // ---- compact candidates to LDS (STATIC d[] indexing -> no scratch)
  #pragma unroll
  for (int j = 0; j < 64; ++j) {
    if (d[j] >= tmf) {
      if (pos < 64) {
        cu_s[w][pos] = f2ord(d[j]);
        cn_s[w][pos] = (j << 6) | lane;
      }
      ++pos;
    }
  }

  // load one candidate per lane (pad lanes sort last)
  unsigned int su = 0u;
  int sn = 0x7FFFFFFF;
  if (lane < ctot) { su = cu_s[w][lane]; sn = cn_s[w][lane]; }

  // ---- bitonic sort, descending by (su, then smaller sn)
  #pragma unroll
  for (int k = 2; k <= 64; k <<= 1) {
    #pragma unroll
    for (int s = k >> 1; s >= 1; s >>= 1) {
      unsigned int ou = __shfl_xor(su, s);
      int          on = __shfl_xor(sn, s);
      bool myMax = ((lane & k) == 0) == ((lane & s) == 0);
      bool beats = (ou > su) || (ou == su && on < sn);
      bool take  = myMax ? beats : !beats;
      su = take ? ou : su;
      sn = take ? on : sn;
    }
  }

  // lanes 1..16 hold ranks 1..16
  if (lane >= 1 && lane <= KNB) {
    grouped4[(size_t)wid * KNB + (lane - 1)] = base[sn];
  }
}

// ---------------------------------------------------------------- mlp
// (unchanged)
__global__ __launch_bounds__(256) void mlp_kernel(
    const float4* __restrict__ grouped4,
    const float*  __restrict__ W0, const float* __restrict__ b0,
    const unsigned short* __restrict__ W1bf, const float* __restrict__ b1,
    const unsigned short* __restrict__ W2bf, const float* __restrict__ b2,
    float* __restrict__ out)
{
  __shared__ float4 g4s[128];
  __shared__ float  W0s[128*4];
  __shared__ float  b0s[128], b1s[128], b2s[128];
  __shared__ unsigned short act[128*128];   // 32 KB

  const int t    = threadIdx.x;
  const int lane = t & 63;
  const int w    = t >> 6;
  const int lr   = lane & 15;
  const int lg   = lane >> 4;
  const int row_base = blockIdx.x * 8;

  if (t < 128) {
    g4s[t] = grouped4[(size_t)row_base * KNB + t];
    float4 w0r;
    w0r.x = W0[t*3+0]; w0r.y = W0[t*3+1]; w0r.z = W0[t*3+2]; w0r.w = 0.0f;
    *(float4*)&W0s[t*4] = w0r;
    b0s[t] = b0[t];
    b1s[t] = b1[t];
    b2s[t] = b2[t];
  }
  __syncthreads();

  // ---- layer 0 (fp32 vector, C=3), write act as bf16
  {
    int r  = t >> 1;
    int cb = (t & 1) * 64;
    float4 g = g4s[r];
    int swz = (r & 7) << 3;
    #pragma unroll
    for (int cc = 0; cc < 8; ++cc) {
      int c0 = cb + cc*8;
      unsigned int pk[4];
      #pragma unroll
      for (int pair = 0; pair < 4; ++pair) {
        unsigned int lo, hi;
        {
          int o = c0 + pair*2;
          float v = b0s[o] + g.x*W0s[o*4] + g.y*W0s[o*4+1] + g.z*W0s[o*4+2];
          lo = f2bf(fmaxf(v, 0.0f));
          o++;
          float v2 = b0s[o] + g.x*W0s[o*4] + g.y*W0s[o*4+1] + g.z*W0s[o*4+2];
          hi = f2bf(fmaxf(v2, 0.0f));
        }
        pk[pair] = lo | (hi << 16);
      }
      uint4 q = make_uint4(pk[0], pk[1], pk[2], pk[3]);
      *(uint4*)&act[r*128 + (c0 ^ swz)] = q;
    }
  }

  const int rt0 = w*2, rt1 = w*2 + 1;
  const int aswz = (lr & 7) << 3;

  // ---- layer 1 (bf16 MFMA), relu, in-place act update
  {
    f32x4 acc[2][8];
    #pragma unroll
    for (int rr = 0; rr < 2; ++rr)
      #pragma unroll
      for (int ct = 0; ct < 8; ++ct)
        acc[rr][ct] = (f32x4){0.f, 0.f, 0.f, 0.f};

    #pragma unroll
    for (int ks = 0; ks < 4; ++ks) {
      int c0 = ks*32 + lg*8;
      bf16x8 a0 = *(const bf16x8*)&act[(rt0*16 + lr)*128 + (c0 ^ aswz)];
      bf16x8 a1 = *(const bf16x8*)&act[(rt1*16 + lr)*128 + (c0 ^ aswz)];
      #pragma unroll
      for (int ct = 0; ct < 8; ++ct) {
        int o = ct*16 + lr;
        bf16x8 bb = *(const bf16x8*)&W1bf[o*128 + c0];
        acc[0][ct] = __builtin_amdgcn_mfma_f32_16x16x32_bf16(a0, bb, acc[0][ct], 0, 0, 0);
        acc[1][ct] = __builtin_amdgcn_mfma_f32_16x16x32_bf16(a1, bb, acc[1][ct], 0, 0, 0);
      }
    }
    #pragma unroll
    for (int rr = 0; rr < 2; ++rr) {
      int rt = rt0 + rr;
      #pragma unroll
      for (int ct = 0; ct < 8; ++ct) {
        int col  = ct*16 + lr;
        float bias = b1s[col];
        #pragma unroll
        for (int i = 0; i < 4; ++i) {
          int row = rt*16 + lg*4 + i;
          float v = acc[rr][ct][i] + bias;
          v = fmaxf(v, 0.0f);
          act[row*128 + (col ^ ((row & 7) << 3))] = f2bf(v);
        }
      }
    }
  }

  // ---- layer 2 (bf16 MFMA), bias, max over k, store
  {
    f32x4 acc[2][8];
    #pragma unroll
    for (int rr = 0; rr < 2; ++rr)
      #pragma unroll
      for (int ct = 0; ct < 8; ++ct)
        acc[rr][ct] = (f32x4){0.f, 0.f, 0.f, 0.f};

    #pragma unroll
    for (int ks = 0; ks < 4; ++ks) {
      int c0 = ks*32 + lg*8;
      bf16x8 a0 = *(const bf16x8*)&act[(rt0*16 + lr)*128 + (c0 ^ aswz)];
      bf16x8 a1 = *(const bf16x8*)&act[(rt1*16 + lr)*128 + (c0 ^ aswz)];
      #pragma unroll
      for (int ct = 0; ct < 8; ++ct) {
        int o = ct*16 + lr;
        bf16x8 bb = *(const bf16x8*)&W2bf[o*128 + c0];
        acc[0][ct] = __builtin_amdgcn_mfma_f32_16x16x32_bf16(a0, bb, acc[0][ct], 0, 0, 0);
        acc[1][ct] = __builtin_amdgcn_mfma_f32_16x16x32_bf16(a1, bb, acc[1][ct], 0, 0, 0);
      }
    }
    #pragma unroll
    for (int rr = 0; rr < 2; ++rr) {
      int p = rt0 + rr;
      #pragma unroll
      for (int ct = 0; ct < 8; ++ct) {
        int col = ct*16 + lr;
        float bias = b2s[col];
        float v0 = acc[rr][ct][0] + bias;
        float va = acc[rr][ct][1] + bias;
        float vb = acc[rr][ct][2] + bias;
        float vc = acc[rr][ct][3] + bias;
        float mx = fmaxf(fmaxf(v0, va), fmaxf(vb, vc));
        mx = fmaxf(mx, __shfl_xor(mx, 16));
        mx = fmaxf(mx, __shfl_xor(mx, 32));
        if (lg == 0) out[(size_t)(row_base + p)*128 + col] = mx;
      }
    }
  }
}

// ---------------------------------------------------------------- launch
extern "C" void kernel_launch(void* const* d_in, const int* in_sizes, int n_in,
                              void* d_out, int out_size, void* d_ws, size_t ws_size,
                              hipStream_t stream) {
  const float* xyz = (const float*)d_in[0];
  const float* W0  = (const float*)d_in[1];
  const float* b0  = (const float*)d_in[2];
  const float* W1  = (const float*)d_in[3];
  const float* b1  = (const float*)d_in[4];
  const float* W2  = (const float*)d_in[5];
  const float* b2  = (const float*)d_in[6];
  float* out = (float*)d_out;

  char* ws = (char*)d_ws;
  float4* xyzw     = (float4*)ws;                              // 512 KB
  float4* grouped4 = (float4*)(ws + (size_t)NROWS*16);         // 8 MB
  unsigned short* W1bf = (unsigned short*)(ws + (size_t)NROWS*16 + (size_t)NROWS*KNB*16);
  unsigned short* W2bf = W1bf + NC*NC;                         // 32 KB each

  prep_kernel<<<NROWS/256, 256, 0, stream>>>(xyz, W1, W2, xyzw, W1bf, W2bf);
  topk_kernel<<<NROWS/4, 256, 0, stream>>>(xyzw, grouped4);
  mlp_kernel<<<NROWS/8, 256, 0, stream>>>(grouped4, W0, b0, W1bf, b1, W2bf, b2, out);
}

// Round 5
// 173.499 us; speedup vs baseline: 2.6576x; 1.5064x over previous
//
#include <hip/hip_runtime.h>

#define BATCH 8
#define NPTS 4096
#define NROWS (BATCH*NPTS)   // 32768
#define KNB 16
#define NC 128

typedef __attribute__((ext_vector_type(8))) short bf16x8;
typedef __attribute__((ext_vector_type(4))) float f32x4;
typedef __attribute__((ext_vector_type(16))) float f32x16;
typedef __attribute__((ext_vector_type(4))) unsigned int u32x4;
typedef __attribute__((ext_vector_type(2))) unsigned int u32x2;

static __device__ __forceinline__ unsigned short f2bf(float f) {
  unsigned u = __float_as_uint(f);
  u = u + 0x7fffu + ((u >> 16) & 1u);   // round-to-nearest-even
  return (unsigned short)(u >> 16);
}

static __device__ __forceinline__ unsigned cvtpk(float lo, float hi) {
  unsigned r;
  asm("v_cvt_pk_bf16_f32 %0, %1, %2" : "=v"(r) : "v"(lo), "v"(hi));
  return r;
}

template<int CTRL>
static __device__ __forceinline__ float dppmax(float v) {
  int mv = __builtin_amdgcn_update_dpp(0, __float_as_int(v), CTRL, 0xf, 0xf, true);
  return fmaxf(v, __int_as_float(mv));
}

// Distance formula — bit-identical everywhere (matches XLA, no contraction).
static __device__ __forceinline__ float dist_f(const float4 pm, const float4 p) {
  #pragma clang fp contract(off)
  float dot = pm.x*p.x + pm.y*p.y + pm.z*p.z;
  return (pm.w + p.w) - 2.0f*dot;
}

static __device__ __forceinline__ unsigned int f2ord(float f) {
  int t = __float_as_int(f);
  return (unsigned int)(t ^ ((t >> 31) | 0x80000000));
}

// ---------------------------------------------------------------- prep
__global__ __launch_bounds__(256) void prep_kernel(
    const float* __restrict__ xyz, const float* __restrict__ W0,
    const float* __restrict__ W1, const float* __restrict__ W2,
    float4* __restrict__ xyzw,
    unsigned short* __restrict__ W1bf, unsigned short* __restrict__ W2bf,
    unsigned short* __restrict__ W0p)
{
  int i = blockIdx.x * 256 + threadIdx.x;
  if (i < NROWS) {
    #pragma clang fp contract(off)
    float x = xyz[3*i], y = xyz[3*i+1], z = xyz[3*i+2];
    float sq = x*x + y*y + z*z;
    xyzw[i] = make_float4(x, y, z, sq);
  }
  if (i < NC*NC) {
    W1bf[i] = f2bf(W1[i]);
    W2bf[i] = f2bf(W2[i]);
  }
  if (i < NC) {
    // split-precision padded W0: [128][16] bf16
    // k0-2: hi(w) (pairs hi(x)), k3-5: hi(w) (pairs lo(x)), k6-8: lo(w) (pairs hi(x))
    #pragma unroll
    for (int c = 0; c < 3; ++c) {
      float v = W0[i*3 + c];
      unsigned short hi = f2bf(v);
      float lof = v - __uint_as_float((unsigned)hi << 16);
      unsigned short lo = f2bf(lof);
      W0p[i*16 + c]     = hi;
      W0p[i*16 + 3 + c] = hi;
      W0p[i*16 + 6 + c] = lo;
    }
    #pragma unroll
    for (int c = 9; c < 16; ++c) W0p[i*16 + c] = 0;
  }
}

// ---------------------------------------------------------------- topk
// (unchanged — known-good from R3)
__global__ __launch_bounds__(256) void topk_kernel(
    const float4* __restrict__ xyzw, float4* __restrict__ grouped4)
{
  __shared__ unsigned int cu_s[4][64];
  __shared__ int          cn_s[4][64];

  const int lane = threadIdx.x & 63;
  const int w    = threadIdx.x >> 6;
  const int wid  = blockIdx.x * 4 + w;
  const int b    = wid >> 12;
  const int m    = wid & (NPTS - 1);
  const float4* base = xyzw + (size_t)b * NPTS;

  const float4 pm = base[m];

  float d[64];
  #pragma unroll
  for (int j = 0; j < 64; ++j) {
    d[j] = dist_f(pm, base[j*64 + lane]);
  }

  float v1 = d[0];
  #pragma unroll
  for (int j = 1; j < 64; ++j) v1 = fmaxf(v1, d[j]);

  unsigned int u1 = f2ord(v1);
  unsigned int cur = 0u;
  #pragma unroll 1
  for (int bit = 31; bit >= 0; --bit) {
    unsigned int cand = cur | (1u << bit);
    if (__popcll(__ballot(u1 >= cand)) >= 17) cur = cand;
  }
  unsigned int ob = (cur & 0x80000000u) ? (cur ^ 0x80000000u) : ~cur;
  const float tmf = __uint_as_float(ob);

  int c = 0;
  #pragma unroll
  for (int j = 0; j < 64; ++j) c += (d[j] >= tmf) ? 1 : 0;

  int pos = c;
  #pragma unroll
  for (int dd = 1; dd < 64; dd <<= 1) {
    int t = __shfl_up(pos, dd);
    if (lane >= dd) pos += t;
  }
  int ctot = __shfl(pos, 63);
  pos -= c;

  #pragma unroll
  for (int j = 0; j < 64; ++j) {
    if (d[j] >= tmf) {
      if (pos < 64) {
        cu_s[w][pos] = f2ord(d[j]);
        cn_s[w][pos] = (j << 6) | lane;
      }
      ++pos;
    }
  }

  unsigned int su = 0u;
  int sn = 0x7FFFFFFF;
  if (lane < ctot) { su = cu_s[w][lane]; sn = cn_s[w][lane]; }

  #pragma unroll
  for (int k = 2; k <= 64; k <<= 1) {
    #pragma unroll
    for (int s = k >> 1; s >= 1; s >>= 1) {
      unsigned int ou = __shfl_xor(su, s);
      int          on = __shfl_xor(sn, s);
      bool myMax = ((lane & k) == 0) == ((lane & s) == 0);
      bool beats = (ou > su) || (ou == su && on < sn);
      bool take  = myMax ? beats : !beats;
      su = take ? ou : su;
      sn = take ? on : sn;
    }
  }

  if (lane >= 1 && lane <= KNB) {
    grouped4[(size_t)wid * KNB + (lane - 1)] = base[sn];
  }
}

// ---------------------------------------------------------------- mlp (v2.1)
// Transposed MFMA pipeline, 32x32x16. D[o][r] lane layout: col=r=lane&31,
// row_in_tile owt=(reg&3)+8*(reg>>2)+4h (h=lane>>5).  Next-layer B-frag f
// needs element e (k=16f+8h+e) = channel owt' = 16(f&1)+8h+e of tile f>>1,
// i.e. acc reg 8(f&1)+4h+(e&3) sourced from half h_src=e>>2.
// Word construction (true permlane32_swap semantics: a_upper <-> b_lower):
//   {word0, word2} = permlane32_swap(P01, P45); {word1, word3} = (P23, P67).

static __device__ __forceinline__ f32x16 zero16() {
  f32x16 v;
  #pragma unroll
  for (int i = 0; i < 16; ++i) v[i] = 0.0f;
  return v;
}

static __device__ __forceinline__ void epi_pack(
    const f32x16 (&acc)[2][4], const float* __restrict__ bias,
    int h, u32x4 (&bfrag)[2][8])
{
  #pragma unroll
  for (int tt = 0; tt < 4; ++tt) {
    float4 bb[4];
    #pragma unroll
    for (int q = 0; q < 4; ++q)
      bb[q] = *(const float4*)&bias[32*tt + 8*q + 4*h];
    #pragma unroll
    for (int nt = 0; nt < 2; ++nt) {
      unsigned P[8];   // P[2q]   = cvtpk(reg 4q,   reg 4q+1)
                       // P[2q+1] = cvtpk(reg 4q+2, reg 4q+3)
      #pragma unroll
      for (int q = 0; q < 4; ++q) {
        float v0 = fmaxf(acc[nt][tt][4*q+0] + bb[q].x, 0.f);
        float v1 = fmaxf(acc[nt][tt][4*q+1] + bb[q].y, 0.f);
        float v2 = fmaxf(acc[nt][tt][4*q+2] + bb[q].z, 0.f);
        float v3 = fmaxf(acc[nt][tt][4*q+3] + bb[q].w, 0.f);
        P[2*q]   = cvtpk(v0, v1);
        P[2*q+1] = cvtpk(v2, v3);
      }
      // even frag f=2tt (regs 0..7):  P01=P[0] P23=P[1] P45=P[2] P67=P[3]
      u32x2 s0 = __builtin_amdgcn_permlane32_swap(P[0], P[2], false, false);
      u32x2 s1 = __builtin_amdgcn_permlane32_swap(P[1], P[3], false, false);
      bfrag[nt][2*tt]   = (u32x4){s0.x, s1.x, s0.y, s1.y};
      // odd frag f=2tt+1 (regs 8..15): P01=P[4] P23=P[5] P45=P[6] P67=P[7]
      u32x2 s2 = __builtin_amdgcn_permlane32_swap(P[4], P[6], false, false);
      u32x2 s3 = __builtin_amdgcn_permlane32_swap(P[5], P[7], false, false);
      bfrag[nt][2*tt+1] = (u32x4){s2.x, s3.x, s2.y, s3.y};
    }
  }
}

static __device__ __forceinline__ void layer_mfma(
    const unsigned short* wl, int l31, int h,
    const u32x4 (&bfrag)[2][8], f32x16 (&acc)[2][4])
{
  const int swz = (l31 & 7) << 4;
  #pragma unroll
  for (int tt = 0; tt < 4; ++tt) {
    const int row = 32*tt + l31;
    #pragma unroll
    for (int f = 0; f < 8; ++f) {
      bf16x8 a = *(const bf16x8*)&wl[row*128 + (((f*32 + h*16) ^ swz) >> 1)];
      acc[0][tt] = __builtin_amdgcn_mfma_f32_32x32x16_bf16(
          a, __builtin_bit_cast(bf16x8, bfrag[0][f]), acc[0][tt], 0, 0, 0);
      acc[1][tt] = __builtin_amdgcn_mfma_f32_32x32x16_bf16(
          a, __builtin_bit_cast(bf16x8, bfrag[1][f]), acc[1][tt], 0, 0, 0);
    }
  }
}

__global__ __launch_bounds__(256) void mlp_kernel(
    const float4* __restrict__ grouped4,
    const unsigned short* __restrict__ W0p, const float* __restrict__ b0,
    const unsigned short* __restrict__ W1bf, const float* __restrict__ b1,
    const unsigned short* __restrict__ W2bf, const float* __restrict__ b2,
    float* __restrict__ out)
{
  __shared__ unsigned short wlds[2*NC*NC];   // 64 KB: W1 | W2, XOR-swizzled rows

  const int t    = threadIdx.x;
  const int lane = t & 63;
  const int w    = t >> 6;
  const int l31  = lane & 31;
  const int h    = lane >> 5;

  // ---- stage W1,W2 -> LDS (reg-staged, swizzled dest)
  #pragma unroll
  for (int it = 0; it < 16; ++it) {
    int e8 = (it*256 + t) * 8;                       // linear short index, 8/thread
    const unsigned short* src = (it < 8) ? (W1bf + e8) : (W2bf + (e8 - NC*NC));
    u32x4 v = *(const u32x4*)src;
    int el  = e8 & (NC*NC - 1);
    int row = el >> 7;
    int cb  = (el & 127) * 2;
    int dst = (e8 & (NC*NC)) + row*128 + (((cb ^ ((row & 7) << 4))) >> 1);
    *(u32x4*)&wlds[dst] = v;
  }
  __syncthreads();

  const int rbase = blockIdx.x*256 + w*64;   // grouped4 row base for this wave
  const int pbase = blockIdx.x*16  + w*4;    // output point base

  float4 g0 = grouped4[rbase + l31];
  float4 g1 = grouped4[rbase + 32 + l31];

  // ---- L0 B-frags: split-precision coords (hi+lo bf16)
  auto mkb0 = [&](const float4& g) -> bf16x8 {
    unsigned short hx = f2bf(g.x), hy = f2bf(g.y), hz = f2bf(g.z);
    float lxf = g.x - __uint_as_float((unsigned)hx << 16);
    float lyf = g.y - __uint_as_float((unsigned)hy << 16);
    float lzf = g.z - __uint_as_float((unsigned)hz << 16);
    unsigned short lx = f2bf(lxf), ly = f2bf(lyf), lz = f2bf(lzf);
    unsigned hxy = (unsigned)hx | ((unsigned)hy << 16);
    u32x4 B;
    B.x = h ? (unsigned)hz : hxy;                            // k0,1 | k8
    B.y = h ? 0u : ((unsigned)hz | ((unsigned)lx << 16));    // k2,3
    B.z = h ? 0u : ((unsigned)ly | ((unsigned)lz << 16));    // k4,5
    B.w = h ? 0u : hxy;                                      // k6,7
    return __builtin_bit_cast(bf16x8, B);
  };
  bf16x8 bf0n0 = mkb0(g0);
  bf16x8 bf0n1 = mkb0(g1);

  f32x16 acc[2][4];
  #pragma unroll
  for (int nt = 0; nt < 2; ++nt)
    #pragma unroll
    for (int tt = 0; tt < 4; ++tt) acc[nt][tt] = zero16();

  // ---- layer 0 (one MFMA per tile; K=16 holds hi*hi + hi*lo + lo*hi)
  #pragma unroll
  for (int tt = 0; tt < 4; ++tt) {
    bf16x8 a = *(const bf16x8*)&W0p[(32*tt + l31)*16 + 8*h];
    acc[0][tt] = __builtin_amdgcn_mfma_f32_32x32x16_bf16(a, bf0n0, acc[0][tt], 0, 0, 0);
    acc[1][tt] = __builtin_amdgcn_mfma_f32_32x32x16_bf16(a, bf0n1, acc[1][tt], 0, 0, 0);
  }

  u32x4 bfrag[2][8];
  epi_pack(acc, b0, h, bfrag);

  // ---- layer 1
  #pragma unroll
  for (int nt = 0; nt < 2; ++nt)
    #pragma unroll
    for (int tt = 0; tt < 4; ++tt) acc[nt][tt] = zero16();
  layer_mfma(&wlds[0], l31, h, bfrag, acc);

  epi_pack(acc, b1, h, bfrag);

  // ---- layer 2
  #pragma unroll
  for (int nt = 0; nt < 2; ++nt)
    #pragma unroll
    for (int tt = 0; tt < 4; ++tt) acc[nt][tt] = zero16();
  layer_mfma(&wlds[NC*NC], l31, h, bfrag, acc);

  // ---- final: max over the 16 neighbors (DPP row reduce) + bias + store
  const int oR = 8*((lane >> 2) & 3) + 4*h + (lane & 3);
  float b2v[4];
  #pragma unroll
  for (int tt = 0; tt < 4; ++tt) b2v[tt] = b2[32*tt + oR];

  #pragma unroll
  for (int nt = 0; nt < 2; ++nt) {
    const int p = pbase + 2*nt + ((lane >> 4) & 1);
    #pragma unroll
    for (int tt = 0; tt < 4; ++tt) {
      float m[16];
      #pragma unroll
      for (int r = 0; r < 16; ++r) {
        float v = acc[nt][tt][r];
        v = dppmax<0xB1>(v);    // quad_perm [1,0,3,2]  (xor 1)
        v = dppmax<0x4E>(v);    // quad_perm [2,3,0,1]  (xor 2)
        v = dppmax<0x124>(v);   // row_ror:4
        v = dppmax<0x128>(v);   // row_ror:8
        m[r] = v;
      }
      float sel = m[0];
      #pragma unroll
      for (int r = 1; r < 16; ++r) sel = ((lane & 15) == r) ? m[r] : sel;
      out[(size_t)p*128 + 32*tt + oR] = sel + b2v[tt];
    }
  }
}

// ---------------------------------------------------------------- launch
extern "C" void kernel_launch(void* const* d_in, const int* in_sizes, int n_in,
                              void* d_out, int out_size, void* d_ws, size_t ws_size,
                              hipStream_t stream) {
  const float* xyz = (const float*)d_in[0];
  const float* W0  = (const float*)d_in[1];
  const float* b0  = (const float*)d_in[2];
  const float* W1  = (const float*)d_in[3];
  const float* b1  = (const float*)d_in[4];
  const float* W2  = (const float*)d_in[5];
  const float* b2  = (const float*)d_in[6];
  float* out = (float*)d_out;

  char* ws = (char*)d_ws;
  float4* xyzw     = (float4*)ws;                              // 512 KB
  float4* grouped4 = (float4*)(ws + (size_t)NROWS*16);         // 8 MB
  unsigned short* W1bf = (unsigned short*)(ws + (size_t)NROWS*16 + (size_t)NROWS*KNB*16);
  unsigned short* W2bf = W1bf + NC*NC;                         // 32 KB each
  unsigned short* W0p  = W2bf + NC*NC;                         // 4 KB

  prep_kernel<<<NROWS/256, 256, 0, stream>>>(xyz, W0, W1, W2, xyzw, W1bf, W2bf, W0p);
  topk_kernel<<<NROWS/4, 256, 0, stream>>>(xyzw, grouped4);
  mlp_kernel<<<NROWS/16, 256, 0, stream>>>(grouped4, W0p, b0, W1bf, b1, W2bf, b2, out);
}